// Round 2
// baseline (1573.829 us; speedup 1.0000x reference)
//
#include <hip/hip_runtime.h>

// GNN NodeModel, round 2: CSR (counting-sort by dest) + register aggregation.
// Replaces 102M f32 atomics (round-1 bottleneck: 159G atomics/s, 400MB HBM
// write-through) with 3.2M int atomics + node-major register accumulation.
//
// Factored math:
//   A1 = x @ W1[0:32],  A2 = x @ W1[32:64]
//   U1[g] = u[g] @ W1[96:128] + b1,  U2[g] = u[g] @ W2[96:128] + b2
//   msg_e = relu(A1[dest] + A2[src] + ea_e @ W1[64:96] + U1[batch[src]])
//   agg[n] = sum over CSR edge list of node n   (registers, no atomics)
//   out = relu(x @ W2[0:32] + agg @ W2[32:96] + U2[batch])

constexpr int kNodes  = 100000;
constexpr int kEdges  = 1600000;
constexpr int kGraphs = 64;
constexpr int kD      = 32;
constexpr int kOut    = 64;
constexpr int SB      = 256;                    // scan block
constexpr int NB      = (kNodes + SB - 1) / SB; // 391 blocks
static_assert(NB <= 512, "scan_top handles <=512 block sums");

// ---------------------------------------------------------------------------
__global__ __launch_bounds__(256) void tables_kernel(
    const float* __restrict__ u, const float* __restrict__ W1,
    const float* __restrict__ b1, const float* __restrict__ W2,
    const float* __restrict__ b2, float* __restrict__ U1,
    float* __restrict__ U2) {
  int t = blockIdx.x * 256 + threadIdx.x;
  if (t >= kGraphs * kOut) return;
  int g = t >> 6, j = t & 63;
  float a1 = b1[j], a2 = b2[j];
#pragma unroll
  for (int k = 0; k < kD; ++k) {
    float uv = u[g * kD + k];
    a1 = fmaf(uv, W1[(96 + k) * kOut + j], a1);
    a2 = fmaf(uv, W2[(96 + k) * kOut + j], a2);
  }
  U1[t] = a1;
  U2[t] = a2;
}

// ---------------------------------------------------------------------------
// A1 = x @ W1[0:32], A2 = x @ W1[32:64]. One wave per node, lane = out col.
__global__ __launch_bounds__(256) void pre_kernel(
    const float* __restrict__ x, const float* __restrict__ W1,
    float* __restrict__ A1, float* __restrict__ A2) {
  __shared__ float sWa[kD * kOut];
  __shared__ float sWb[kD * kOut];
  for (int i = threadIdx.x; i < kD * kOut; i += 256) {
    sWa[i] = W1[i];
    sWb[i] = W1[kD * kOut + i];
  }
  __syncthreads();
  const int lane = threadIdx.x & 63;
  const int wave = (blockIdx.x * 256 + threadIdx.x) >> 6;
  const int nw   = gridDim.x * 4;
  for (int n = wave; n < kNodes; n += nw) {
    const float4* xr = reinterpret_cast<const float4*>(x + (size_t)n * kD);
    float a1 = 0.f, a2 = 0.f;
#pragma unroll
    for (int q = 0; q < 8; ++q) {
      float4 v = xr[q];
      int k = q * 4;
      a1 = fmaf(v.x, sWa[(k + 0) * kOut + lane], a1);
      a1 = fmaf(v.y, sWa[(k + 1) * kOut + lane], a1);
      a1 = fmaf(v.z, sWa[(k + 2) * kOut + lane], a1);
      a1 = fmaf(v.w, sWa[(k + 3) * kOut + lane], a1);
      a2 = fmaf(v.x, sWb[(k + 0) * kOut + lane], a2);
      a2 = fmaf(v.y, sWb[(k + 1) * kOut + lane], a2);
      a2 = fmaf(v.z, sWb[(k + 2) * kOut + lane], a2);
      a2 = fmaf(v.w, sWb[(k + 3) * kOut + lane], a2);
    }
    A1[(size_t)n * kOut + lane] = a1;
    A2[(size_t)n * kOut + lane] = a2;
  }
}

// ---------------------------------------------------------------------------
__global__ __launch_bounds__(256) void hist_kernel(const int* __restrict__ ei,
                                                   int* __restrict__ counts) {
  int i = blockIdx.x * 256 + threadIdx.x;
  int stride = gridDim.x * 256;
  for (int e = i; e < kEdges; e += stride)
    atomicAdd(&counts[ei[kEdges + e]], 1);
}

__global__ __launch_bounds__(SB) void scan_reduce(const int* __restrict__ counts,
                                                  int* __restrict__ bsum) {
  __shared__ int s[SB];
  int i = blockIdx.x * SB + threadIdx.x;
  s[threadIdx.x] = (i < kNodes) ? counts[i] : 0;
  __syncthreads();
  for (int off = SB / 2; off > 0; off >>= 1) {
    if (threadIdx.x < off) s[threadIdx.x] += s[threadIdx.x + off];
    __syncthreads();
  }
  if (threadIdx.x == 0) bsum[blockIdx.x] = s[0];
}

__global__ __launch_bounds__(512) void scan_top(int* __restrict__ bsum) {
  __shared__ int s[512];
  int t = threadIdx.x;
  int orig = (t < NB) ? bsum[t] : 0;
  s[t] = orig;
  __syncthreads();
  for (int off = 1; off < 512; off <<= 1) {
    int a = (t >= off) ? s[t - off] : 0;
    __syncthreads();
    s[t] += a;
    __syncthreads();
  }
  if (t < NB) bsum[t] = s[t] - orig;  // exclusive
}

__global__ __launch_bounds__(SB) void scan_final(
    const int* __restrict__ counts, const int* __restrict__ bscan,
    int* __restrict__ offs, int* __restrict__ cursor) {
  __shared__ int s[SB];
  int i = blockIdx.x * SB + threadIdx.x;
  int v = (i < kNodes) ? counts[i] : 0;
  s[threadIdx.x] = v;
  __syncthreads();
  for (int off = 1; off < SB; off <<= 1) {
    int a = (threadIdx.x >= off) ? s[threadIdx.x - off] : 0;
    __syncthreads();
    s[threadIdx.x] += a;
    __syncthreads();
  }
  if (i < kNodes) {
    int ex = s[threadIdx.x] - v + bscan[blockIdx.x];
    offs[i] = ex;
    cursor[i] = ex;
  }
  if (blockIdx.x == 0 && threadIdx.x == 0) offs[kNodes] = kEdges;
}

__global__ __launch_bounds__(256) void scatter_kernel(
    const int* __restrict__ ei, int* __restrict__ cursor,
    int2* __restrict__ sorted) {
  int i = blockIdx.x * 256 + threadIdx.x;
  int stride = gridDim.x * 256;
  for (int e = i; e < kEdges; e += stride) {
    int s = ei[e];
    int d = ei[kEdges + e];
    int pos = atomicAdd(&cursor[d], 1);
    sorted[pos] = make_int2(e, s);
  }
}

// ---------------------------------------------------------------------------
// One wave per node: walk CSR list, recompute factored message, accumulate in
// registers. W1[64:96] column lives in 32 VGPRs. Zero atomics.
__global__ __launch_bounds__(256) void agg_kernel(
    const int2* __restrict__ sorted, const int* __restrict__ offs,
    const int* __restrict__ batch, const float* __restrict__ ea,
    const float* __restrict__ A1, const float* __restrict__ A2,
    const float* __restrict__ U1, const float* __restrict__ W1,
    float* __restrict__ agg) {
  const int lane = threadIdx.x & 63;
  float wreg[kD];
#pragma unroll
  for (int k = 0; k < kD; ++k)
    wreg[k] = W1[(size_t)(2 * kD + k) * kOut + lane];
  const int wave = (blockIdx.x * 256 + threadIdx.x) >> 6;
  const int nw   = gridDim.x * 4;
  for (int n = wave; n < kNodes; n += nw) {
    const float a1 = A1[(size_t)n * kOut + lane];
    const int beg = offs[n], end = offs[n + 1];
    float aggl = 0.f;
    for (int idx = beg; idx < end; ++idx) {
      int2 es = sorted[idx];
      const int e = es.x, s = es.y;
      const int g = batch[s];
      float m0 = a1 + U1[g * kOut + lane];
      float m1 = A2[(size_t)s * kOut + lane];
      float m2 = 0.f, m3 = 0.f;
      const float4* er = reinterpret_cast<const float4*>(ea + (size_t)e * kD);
#pragma unroll
      for (int q = 0; q < 8; ++q) {
        float4 v = er[q];
        m0 = fmaf(v.x, wreg[4 * q + 0], m0);
        m1 = fmaf(v.y, wreg[4 * q + 1], m1);
        m2 = fmaf(v.z, wreg[4 * q + 2], m2);
        m3 = fmaf(v.w, wreg[4 * q + 3], m3);
      }
      aggl += fmaxf((m0 + m1) + (m2 + m3), 0.f);
    }
    agg[(size_t)n * kOut + lane] = aggl;
  }
}

// ---------------------------------------------------------------------------
// out = relu(x @ W2[0:32] + agg @ W2[32:96] + U2[batch]). One wave per node.
__global__ __launch_bounds__(256) void mlp2_kernel(
    const float* __restrict__ x, const float* __restrict__ agg,
    const int* __restrict__ batch, const float* __restrict__ U2,
    const float* __restrict__ W2, float* __restrict__ out) {
  __shared__ float sWa[kD * kOut];    // W2 rows 0..31  (x block)
  __shared__ float sWb[kOut * kOut];  // W2 rows 32..95 (agg block)
  for (int i = threadIdx.x; i < kD * kOut; i += 256) sWa[i] = W2[i];
  for (int i = threadIdx.x; i < kOut * kOut; i += 256)
    sWb[i] = W2[kD * kOut + i];
  __syncthreads();
  const int lane = threadIdx.x & 63;
  const int wave = (blockIdx.x * 256 + threadIdx.x) >> 6;
  const int nw   = gridDim.x * 4;
  for (int n = wave; n < kNodes; n += nw) {
    const int g = batch[n];
    float acc = U2[g * kOut + lane];
    const float4* xr = reinterpret_cast<const float4*>(x + (size_t)n * kD);
#pragma unroll
    for (int q = 0; q < 8; ++q) {
      float4 v = xr[q];
      int k = q * 4;
      acc = fmaf(v.x, sWa[(k + 0) * kOut + lane], acc);
      acc = fmaf(v.y, sWa[(k + 1) * kOut + lane], acc);
      acc = fmaf(v.z, sWa[(k + 2) * kOut + lane], acc);
      acc = fmaf(v.w, sWa[(k + 3) * kOut + lane], acc);
    }
    const float4* ar = reinterpret_cast<const float4*>(agg + (size_t)n * kOut);
#pragma unroll
    for (int q = 0; q < 16; ++q) {
      float4 v = ar[q];
      int k = q * 4;
      acc = fmaf(v.x, sWb[(k + 0) * kOut + lane], acc);
      acc = fmaf(v.y, sWb[(k + 1) * kOut + lane], acc);
      acc = fmaf(v.z, sWb[(k + 2) * kOut + lane], acc);
      acc = fmaf(v.w, sWb[(k + 3) * kOut + lane], acc);
    }
    out[(size_t)n * kOut + lane] = fmaxf(acc, 0.f);
  }
}

// ---------------------------------------------------------------------------
extern "C" void kernel_launch(void* const* d_in, const int* in_sizes, int n_in,
                              void* d_out, int out_size, void* d_ws,
                              size_t ws_size, hipStream_t stream) {
  const float* x     = (const float*)d_in[0];
  const int*   ei    = (const int*)d_in[1];
  const float* ea    = (const float*)d_in[2];
  const float* u     = (const float*)d_in[3];
  const int*   batch = (const int*)d_in[4];
  const float* W1    = (const float*)d_in[5];
  const float* b1    = (const float*)d_in[6];
  const float* W2    = (const float*)d_in[7];
  const float* b2    = (const float*)d_in[8];
  float* out = (float*)d_out;

  // Workspace layout (~92 MB).
  float* A1     = (float*)d_ws;
  float* A2     = A1 + (size_t)kNodes * kOut;
  float* agg    = A2 + (size_t)kNodes * kOut;
  int2*  sorted = (int2*)(agg + (size_t)kNodes * kOut);
  float* U1     = (float*)(sorted + kEdges);
  float* U2     = U1 + kGraphs * kOut;
  int*   counts = (int*)(U2 + kGraphs * kOut);
  int*   offs   = counts + kNodes;       // kNodes+1 entries
  int*   cursor = offs + kNodes + 1;
  int*   bsum   = cursor + kNodes;       // NB entries

  hipMemsetAsync(counts, 0, (size_t)kNodes * sizeof(int), stream);
  tables_kernel<<<(kGraphs * kOut + 255) / 256, 256, 0, stream>>>(
      u, W1, b1, W2, b2, U1, U2);
  pre_kernel<<<1024, 256, 0, stream>>>(x, W1, A1, A2);
  hist_kernel<<<2048, 256, 0, stream>>>(ei, counts);
  scan_reduce<<<NB, SB, 0, stream>>>(counts, bsum);
  scan_top<<<1, 512, 0, stream>>>(bsum);
  scan_final<<<NB, SB, 0, stream>>>(counts, bsum, offs, cursor);
  scatter_kernel<<<2048, 256, 0, stream>>>(ei, cursor, sorted);
  agg_kernel<<<2048, 256, 0, stream>>>(sorted, offs, batch, ea, A1, A2, U1, W1,
                                       agg);
  mlp2_kernel<<<1024, 256, 0, stream>>>(x, agg, batch, U2, W2, out);
}

// Round 3
// 1221.072 us; speedup vs baseline: 1.2889x; 1.2889x over previous
//
#include <hip/hip_runtime.h>

// GNN NodeModel, round 3: CSR + node-partitioned edge-parallel LDS aggregation.
// R1 lesson: 102M global f32 atomics = 159 G/s wall (645 us).
// R2 lesson: per-node serial CSR walk = latency-bound (980 us, VALU 16%, HBM 4%).
// R3: each block owns 64 dest-sorted nodes; 4 waves walk the block's edge range
// edge-parallel (independent iterations), accumulate messages into LDS via
// ds_add_f32, then one plain coalesced store per node. No global f32 atomics,
// no serial per-node chains.
//
// Factored math:
//   A1 = x @ W1[0:32],  A2 = x @ W1[32:64]
//   U1[g] = u[g] @ W1[96:128] + b1,  U2[g] = u[g] @ W2[96:128] + b2
//   msg_e = relu(A1[dest] + A2[src] + ea_e @ W1[64:96] + U1[batch[src]])
//   agg[n] = sum of msg over CSR range of n
//   out = relu(x @ W2[0:32] + agg @ W2[32:96] + U2[batch])

constexpr int kNodes  = 100000;
constexpr int kEdges  = 1600000;
constexpr int kGraphs = 64;
constexpr int kD      = 32;
constexpr int kOut    = 64;
constexpr int SB      = 256;
constexpr int NB      = (kNodes + SB - 1) / SB;  // 391 scan blocks
constexpr int NPB     = 64;                      // nodes per agg block
constexpr int NAB     = (kNodes + NPB - 1) / NPB;
static_assert(NB <= 512, "scan_top handles <=512 block sums");

// ---------------------------------------------------------------------------
__global__ __launch_bounds__(256) void tables_kernel(
    const float* __restrict__ u, const float* __restrict__ W1,
    const float* __restrict__ b1, const float* __restrict__ W2,
    const float* __restrict__ b2, float* __restrict__ U1,
    float* __restrict__ U2) {
  int t = blockIdx.x * 256 + threadIdx.x;
  if (t >= kGraphs * kOut) return;
  int g = t >> 6, j = t & 63;
  float a1 = b1[j], a2 = b2[j];
#pragma unroll
  for (int k = 0; k < kD; ++k) {
    float uv = u[g * kD + k];
    a1 = fmaf(uv, W1[(96 + k) * kOut + j], a1);
    a2 = fmaf(uv, W2[(96 + k) * kOut + j], a2);
  }
  U1[t] = a1;
  U2[t] = a2;
}

// ---------------------------------------------------------------------------
// A1 = x @ W1[0:32], A2 = x @ W1[32:64]. One wave per node, lane = out col.
__global__ __launch_bounds__(256) void pre_kernel(
    const float* __restrict__ x, const float* __restrict__ W1,
    float* __restrict__ A1, float* __restrict__ A2) {
  __shared__ float sWa[kD * kOut];
  __shared__ float sWb[kD * kOut];
  for (int i = threadIdx.x; i < kD * kOut; i += 256) {
    sWa[i] = W1[i];
    sWb[i] = W1[kD * kOut + i];
  }
  __syncthreads();
  const int lane = threadIdx.x & 63;
  const int wave = (blockIdx.x * 256 + threadIdx.x) >> 6;
  const int nw   = gridDim.x * 4;
  for (int n = wave; n < kNodes; n += nw) {
    const float4* xr = reinterpret_cast<const float4*>(x + (size_t)n * kD);
    float a1 = 0.f, a2 = 0.f;
#pragma unroll
    for (int q = 0; q < 8; ++q) {
      float4 v = xr[q];
      int k = q * 4;
      a1 = fmaf(v.x, sWa[(k + 0) * kOut + lane], a1);
      a1 = fmaf(v.y, sWa[(k + 1) * kOut + lane], a1);
      a1 = fmaf(v.z, sWa[(k + 2) * kOut + lane], a1);
      a1 = fmaf(v.w, sWa[(k + 3) * kOut + lane], a1);
      a2 = fmaf(v.x, sWb[(k + 0) * kOut + lane], a2);
      a2 = fmaf(v.y, sWb[(k + 1) * kOut + lane], a2);
      a2 = fmaf(v.z, sWb[(k + 2) * kOut + lane], a2);
      a2 = fmaf(v.w, sWb[(k + 3) * kOut + lane], a2);
    }
    A1[(size_t)n * kOut + lane] = a1;
    A2[(size_t)n * kOut + lane] = a2;
  }
}

// ---------------------------------------------------------------------------
__global__ __launch_bounds__(256) void hist_kernel(const int* __restrict__ ei,
                                                   int* __restrict__ counts) {
  int i = blockIdx.x * 256 + threadIdx.x;
  int stride = gridDim.x * 256;
  for (int e = i; e < kEdges; e += stride)
    atomicAdd(&counts[ei[kEdges + e]], 1);
}

__global__ __launch_bounds__(SB) void scan_reduce(const int* __restrict__ counts,
                                                  int* __restrict__ bsum) {
  __shared__ int s[SB];
  int i = blockIdx.x * SB + threadIdx.x;
  s[threadIdx.x] = (i < kNodes) ? counts[i] : 0;
  __syncthreads();
  for (int off = SB / 2; off > 0; off >>= 1) {
    if (threadIdx.x < off) s[threadIdx.x] += s[threadIdx.x + off];
    __syncthreads();
  }
  if (threadIdx.x == 0) bsum[blockIdx.x] = s[0];
}

__global__ __launch_bounds__(512) void scan_top(int* __restrict__ bsum) {
  __shared__ int s[512];
  int t = threadIdx.x;
  int orig = (t < NB) ? bsum[t] : 0;
  s[t] = orig;
  __syncthreads();
  for (int off = 1; off < 512; off <<= 1) {
    int a = (t >= off) ? s[t - off] : 0;
    __syncthreads();
    s[t] += a;
    __syncthreads();
  }
  if (t < NB) bsum[t] = s[t] - orig;  // exclusive
}

__global__ __launch_bounds__(SB) void scan_final(
    const int* __restrict__ counts, const int* __restrict__ bscan,
    int* __restrict__ offs, int* __restrict__ cursor) {
  __shared__ int s[SB];
  int i = blockIdx.x * SB + threadIdx.x;
  int v = (i < kNodes) ? counts[i] : 0;
  s[threadIdx.x] = v;
  __syncthreads();
  for (int off = 1; off < SB; off <<= 1) {
    int a = (threadIdx.x >= off) ? s[threadIdx.x - off] : 0;
    __syncthreads();
    s[threadIdx.x] += a;
    __syncthreads();
  }
  if (i < kNodes) {
    int ex = s[threadIdx.x] - v + bscan[blockIdx.x];
    offs[i] = ex;
    cursor[i] = ex;
  }
  if (blockIdx.x == 0 && threadIdx.x == 0) offs[kNodes] = kEdges;
}

// Pack (e, s, g, d) into 61 bits: e<2^21, s<2^17, g<2^6, d<2^17.
__global__ __launch_bounds__(256) void scatter_kernel(
    const int* __restrict__ ei, const int* __restrict__ batch,
    int* __restrict__ cursor, unsigned long long* __restrict__ sorted8) {
  int i = blockIdx.x * 256 + threadIdx.x;
  int stride = gridDim.x * 256;
  for (int e = i; e < kEdges; e += stride) {
    int s = ei[e];
    int d = ei[kEdges + e];
    int g = batch[s];
    int pos = atomicAdd(&cursor[d], 1);
    unsigned long long v = (unsigned long long)e |
                           ((unsigned long long)s << 21) |
                           ((unsigned long long)g << 38) |
                           ((unsigned long long)d << 44);
    sorted8[pos] = v;
  }
}

// ---------------------------------------------------------------------------
// Block owns nodes [n0, n0+NPB): 4 waves walk the block's dest-sorted edge
// range edge-parallel; independent iterations accumulate into LDS via
// ds_add_f32; final plain coalesced store. lane = output column.
__global__ __launch_bounds__(256) void agg2_kernel(
    const unsigned long long* __restrict__ sorted8,
    const int* __restrict__ offs, const float* __restrict__ ea,
    const float* __restrict__ A1, const float* __restrict__ A2,
    const float* __restrict__ U1, const float* __restrict__ W1,
    float* __restrict__ agg) {
  __shared__ float acc[NPB * kOut];  // 16 KB
  const int tid  = threadIdx.x;
  const int lane = tid & 63;
  const int wv   = tid >> 6;  // 0..3
  float wreg[kD];
#pragma unroll
  for (int k = 0; k < kD; ++k)
    wreg[k] = W1[(size_t)(2 * kD + k) * kOut + lane];
  for (int i = tid; i < NPB * kOut; i += 256) acc[i] = 0.f;
  __syncthreads();
  const int n0 = blockIdx.x * NPB;
  const int n1 = min(n0 + NPB, kNodes);
  const int ebeg = offs[n0], eend = offs[n1];
#pragma unroll 2
  for (int idx = ebeg + wv; idx < eend; idx += 4) {
    const unsigned long long v = sorted8[idx];
    const int e = (int)(v & 0x1FFFFFull);
    const int s = (int)((v >> 21) & 0x1FFFFull);
    const int g = (int)((v >> 38) & 0x3Full);
    const int d = (int)(v >> 44);
    float m0 = A1[(size_t)d * kOut + lane] + U1[g * kOut + lane];
    float m1 = A2[(size_t)s * kOut + lane];
    const float4* er = reinterpret_cast<const float4*>(ea + (size_t)e * kD);
#pragma unroll
    for (int q = 0; q < 8; ++q) {
      float4 vv = er[q];
      m0 = fmaf(vv.x, wreg[4 * q + 0], m0);
      m1 = fmaf(vv.y, wreg[4 * q + 1], m1);
      m0 = fmaf(vv.z, wreg[4 * q + 2], m0);
      m1 = fmaf(vv.w, wreg[4 * q + 3], m1);
    }
    unsafeAtomicAdd(&acc[(d - n0) * kOut + lane], fmaxf(m0 + m1, 0.f));
  }
  __syncthreads();
  for (int r = wv; r < n1 - n0; r += 4)
    agg[(size_t)(n0 + r) * kOut + lane] = acc[r * kOut + lane];
}

// ---------------------------------------------------------------------------
// out = relu(x @ W2[0:32] + agg @ W2[32:96] + U2[batch]). One wave per node.
__global__ __launch_bounds__(256) void mlp2_kernel(
    const float* __restrict__ x, const float* __restrict__ agg,
    const int* __restrict__ batch, const float* __restrict__ U2,
    const float* __restrict__ W2, float* __restrict__ out) {
  __shared__ float sWa[kD * kOut];    // W2 rows 0..31  (x block)
  __shared__ float sWb[kOut * kOut];  // W2 rows 32..95 (agg block)
  for (int i = threadIdx.x; i < kD * kOut; i += 256) sWa[i] = W2[i];
  for (int i = threadIdx.x; i < kOut * kOut; i += 256)
    sWb[i] = W2[kD * kOut + i];
  __syncthreads();
  const int lane = threadIdx.x & 63;
  const int wave = (blockIdx.x * 256 + threadIdx.x) >> 6;
  const int nw   = gridDim.x * 4;
  for (int n = wave; n < kNodes; n += nw) {
    const int g = batch[n];
    float acc = U2[g * kOut + lane];
    const float4* xr = reinterpret_cast<const float4*>(x + (size_t)n * kD);
#pragma unroll
    for (int q = 0; q < 8; ++q) {
      float4 v = xr[q];
      int k = q * 4;
      acc = fmaf(v.x, sWa[(k + 0) * kOut + lane], acc);
      acc = fmaf(v.y, sWa[(k + 1) * kOut + lane], acc);
      acc = fmaf(v.z, sWa[(k + 2) * kOut + lane], acc);
      acc = fmaf(v.w, sWa[(k + 3) * kOut + lane], acc);
    }
    const float4* ar = reinterpret_cast<const float4*>(agg + (size_t)n * kOut);
#pragma unroll
    for (int q = 0; q < 16; ++q) {
      float4 v = ar[q];
      int k = q * 4;
      acc = fmaf(v.x, sWb[(k + 0) * kOut + lane], acc);
      acc = fmaf(v.y, sWb[(k + 1) * kOut + lane], acc);
      acc = fmaf(v.z, sWb[(k + 2) * kOut + lane], acc);
      acc = fmaf(v.w, sWb[(k + 3) * kOut + lane], acc);
    }
    out[(size_t)n * kOut + lane] = fmaxf(acc, 0.f);
  }
}

// ---------------------------------------------------------------------------
extern "C" void kernel_launch(void* const* d_in, const int* in_sizes, int n_in,
                              void* d_out, int out_size, void* d_ws,
                              size_t ws_size, hipStream_t stream) {
  const float* x     = (const float*)d_in[0];
  const int*   ei    = (const int*)d_in[1];
  const float* ea    = (const float*)d_in[2];
  const float* u     = (const float*)d_in[3];
  const int*   batch = (const int*)d_in[4];
  const float* W1    = (const float*)d_in[5];
  const float* b1    = (const float*)d_in[6];
  const float* W2    = (const float*)d_in[7];
  const float* b2    = (const float*)d_in[8];
  float* out = (float*)d_out;

  // Workspace layout (~91 MB, matches round-2 proven footprint).
  float* A1 = (float*)d_ws;
  float* A2 = A1 + (size_t)kNodes * kOut;
  float* agg = A2 + (size_t)kNodes * kOut;
  unsigned long long* sorted8 =
      (unsigned long long*)(agg + (size_t)kNodes * kOut);
  float* U1   = (float*)(sorted8 + kEdges);
  float* U2   = U1 + kGraphs * kOut;
  int* counts = (int*)(U2 + kGraphs * kOut);
  int* offs   = counts + kNodes;  // kNodes+1 entries
  int* cursor = offs + kNodes + 1;
  int* bsum   = cursor + kNodes;  // NB entries

  hipMemsetAsync(counts, 0, (size_t)kNodes * sizeof(int), stream);
  tables_kernel<<<(kGraphs * kOut + 255) / 256, 256, 0, stream>>>(
      u, W1, b1, W2, b2, U1, U2);
  pre_kernel<<<1024, 256, 0, stream>>>(x, W1, A1, A2);
  hist_kernel<<<2048, 256, 0, stream>>>(ei, counts);
  scan_reduce<<<NB, SB, 0, stream>>>(counts, bsum);
  scan_top<<<1, 512, 0, stream>>>(bsum);
  scan_final<<<NB, SB, 0, stream>>>(counts, bsum, offs, cursor);
  scatter_kernel<<<2048, 256, 0, stream>>>(ei, batch, cursor, sorted8);
  agg2_kernel<<<NAB, 256, 0, stream>>>(sorted8, offs, ea, A1, A2, U1, W1, agg);
  mlp2_kernel<<<1024, 256, 0, stream>>>(x, agg, batch, U2, W2, out);
}